// Round 1
// baseline (370.866 us; speedup 1.0000x reference)
//
#include <hip/hip_runtime.h>
#include <hip/hip_bf16.h>

// EdgeBlock: out[e] = relu(concat(edge[e], node[recv[e]], node[send[e]], g) @ W1 + b1) @ W2 + b2
// Strategy: bf16 MFMA (16x16x32), global-attr term prefolded into acc init (K=192),
// A-fragments gathered straight from global (no LDS for GEMM1), hidden re-fragmented via LDS.

typedef __bf16 bf16x8 __attribute__((ext_vector_type(8)));
typedef float f32x4 __attribute__((ext_vector_type(4)));

#define BM 64
#define D_HID 128
#define D_OUT 64
#define K1 192

// ws layout:
//   [0, 49152)          W1T bf16 [128][192]   (W1T[n][k] = W1[k][n], k<192)
//   [49152, 65536)      W2T bf16 [64][128]    (W2T[n][k] = W2[k][n])
//   [65536, 66048)      g1  f32  [128]        (b1 + global_attr @ W1[192:256])

__global__ void prep_kernel(const float* __restrict__ W1, const float* __restrict__ b1,
                            const float* __restrict__ W2, const float* __restrict__ gattr,
                            __bf16* __restrict__ W1T, __bf16* __restrict__ W2T,
                            float* __restrict__ g1) {
    int tid = blockIdx.x * blockDim.x + threadIdx.x;
    if (tid < 128 * 192) {
        int n = tid / 192, k = tid % 192;
        W1T[n * 192 + k] = (__bf16)W1[k * 128 + n];
    } else if (tid < 128 * 192 + 64 * 128) {
        int t = tid - 128 * 192;
        int n = t / 128, k = t % 128;
        W2T[n * 128 + k] = (__bf16)W2[k * 64 + n];
    } else if (tid < 128 * 192 + 64 * 128 + 128) {
        int n = tid - (128 * 192 + 64 * 128);
        float acc = b1[n];
        for (int j = 0; j < 64; ++j) acc += gattr[j] * W1[(192 + j) * 128 + n];
        g1[n] = acc;
    }
}

__device__ __forceinline__ f32x4 mk4(float v) {
    f32x4 r; r[0] = v; r[1] = v; r[2] = v; r[3] = v; return r;
}

__global__ __launch_bounds__(256) void edge_mlp_kernel(
    const float* __restrict__ edge_feats, const float* __restrict__ node_feats,
    const int* __restrict__ senders, const int* __restrict__ receivers,
    const __bf16* __restrict__ W1T, const __bf16* __restrict__ W2T,
    const float* __restrict__ g1, const float* __restrict__ b2,
    float* __restrict__ out, int E)
{
    __shared__ __bf16 h_lds[64][136];  // 128 cols padded to 136 (17408 B)

    const int e0   = blockIdx.x * BM;
    const int lane = threadIdx.x & 63;
    const int w    = threadIdx.x >> 6;   // wave 0..3
    const int c    = lane & 15;          // col-in-tile / A-row-in-tile
    const int g    = lane >> 4;          // k-group 0..3

    // Per-m-tile source row pointers (A rows = edges). E % 64 == 0 for this
    // problem; clamp anyway so stray rows never produce wild gathers.
    const float* pe[4]; const float* pr[4]; const float* ps[4];
#pragma unroll
    for (int mt = 0; mt < 4; ++mt) {
        int row = e0 + mt * 16 + c;
        if (row > E - 1) row = E - 1;
        pe[mt] = edge_feats + (long)row * 64;
        pr[mt] = node_feats + (long)receivers[row] * 64;
        ps[mt] = node_feats + (long)senders[row] * 64;
    }

    // ---- GEMM1: h = relu([edge|recv|send] @ W1[0:192] + g1) ----
    f32x4 acc[4][2];
#pragma unroll
    for (int nt = 0; nt < 2; ++nt) {
        float v = g1[(2 * w + nt) * 16 + c];
#pragma unroll
        for (int mt = 0; mt < 4; ++mt) acc[mt][nt] = mk4(v);
    }

#pragma unroll
    for (int ks = 0; ks < 6; ++ks) {
        bf16x8 bfr[2];
#pragma unroll
        for (int nt = 0; nt < 2; ++nt) {
            const __bf16* bp = W1T + ((2 * w + nt) * 16 + c) * K1 + ks * 32 + g * 8;
            bfr[nt] = *(const bf16x8*)bp;
        }
#pragma unroll
        for (int mt = 0; mt < 4; ++mt) {
            // seg = ks/2 is compile-time under unroll: 0,1->edge  2,3->recv  4,5->send
            const float* base = (ks < 2) ? pe[mt] : (ks < 4) ? pr[mt] : ps[mt];
            const float* p = base + (ks & 1) * 32 + g * 8;
            f32x4 lo = *(const f32x4*)p;
            f32x4 hi = *(const f32x4*)(p + 4);
            bf16x8 a;
            a[0] = (__bf16)lo[0]; a[1] = (__bf16)lo[1]; a[2] = (__bf16)lo[2]; a[3] = (__bf16)lo[3];
            a[4] = (__bf16)hi[0]; a[5] = (__bf16)hi[1]; a[6] = (__bf16)hi[2]; a[7] = (__bf16)hi[3];
#pragma unroll
            for (int nt = 0; nt < 2; ++nt)
                acc[mt][nt] = __builtin_amdgcn_mfma_f32_16x16x32_bf16(a, bfr[nt], acc[mt][nt], 0, 0, 0);
        }
    }

    // relu + bf16, stash hidden tile in LDS (D layout: col=lane&15, row=(lane>>4)*4+r)
#pragma unroll
    for (int mt = 0; mt < 4; ++mt)
#pragma unroll
        for (int nt = 0; nt < 2; ++nt)
#pragma unroll
            for (int r = 0; r < 4; ++r) {
                float v = acc[mt][nt][r];
                v = v > 0.f ? v : 0.f;
                h_lds[mt * 16 + g * 4 + r][(2 * w + nt) * 16 + c] = (__bf16)v;
            }
    __syncthreads();

    // ---- GEMM2: out = h @ W2 + b2 ; each wave owns one 16-col n-tile ----
    f32x4 acc2[4];
    {
        float bv = b2[w * 16 + c];
#pragma unroll
        for (int mt = 0; mt < 4; ++mt) acc2[mt] = mk4(bv);
    }
#pragma unroll
    for (int ks = 0; ks < 4; ++ks) {
        bf16x8 b2f = *(const bf16x8*)(W2T + (w * 16 + c) * 128 + ks * 32 + g * 8);
#pragma unroll
        for (int mt = 0; mt < 4; ++mt) {
            bf16x8 a2 = *(const bf16x8*)&h_lds[mt * 16 + c][ks * 32 + g * 8];
            acc2[mt] = __builtin_amdgcn_mfma_f32_16x16x32_bf16(a2, b2f, acc2[mt], 0, 0, 0);
        }
    }

#pragma unroll
    for (int mt = 0; mt < 4; ++mt)
#pragma unroll
        for (int r = 0; r < 4; ++r) {
            int row = e0 + mt * 16 + g * 4 + r;
            if (row < E) out[(long)row * 64 + w * 16 + c] = acc2[mt][r];
        }
}

extern "C" void kernel_launch(void* const* d_in, const int* in_sizes, int n_in,
                              void* d_out, int out_size, void* d_ws, size_t ws_size,
                              hipStream_t stream) {
    const float* edge_feats = (const float*)d_in[0];
    const float* node_feats = (const float*)d_in[1];
    const float* gattr      = (const float*)d_in[2];
    const int*   senders    = (const int*)d_in[3];
    const int*   receivers  = (const int*)d_in[4];
    const float* W1         = (const float*)d_in[5];
    const float* b1         = (const float*)d_in[6];
    const float* W2         = (const float*)d_in[7];
    const float* b2         = (const float*)d_in[8];
    float* out = (float*)d_out;

    char* ws = (char*)d_ws;
    __bf16* W1T = (__bf16*)ws;
    __bf16* W2T = (__bf16*)(ws + 49152);
    float*  g1  = (float*)(ws + 49152 + 16384);

    int prep_total = 128 * 192 + 64 * 128 + 128;
    int prep_blocks = (prep_total + 255) / 256;
    prep_kernel<<<prep_blocks, 256, 0, stream>>>(W1, b1, W2, gattr, W1T, W2T, g1);

    const int E = in_sizes[3];  // senders count = N_EDGES
    int grid = (E + BM - 1) / BM;
    edge_mlp_kernel<<<grid, 256, 0, stream>>>(edge_feats, node_feats, senders, receivers,
                                              W1T, W2T, g1, b2, out, E);
}